// Round 1
// baseline (284.167 us; speedup 1.0000x reference)
//
#include <hip/hip_runtime.h>
#include <math.h>

// ECE loss: per-row softmax-max confidence + argmax prediction, binned
// histogram over (pred_class, conf_bin) cells, ECE = sum|sum_conf-sum_acc|/N.
//
// Workspace layout (d_ws as float*):
//   [0 .. num_cells)              sum_conf per cell
//   [num_cells .. 2*num_cells)    sum_acc  per cell

__global__ void ece_zero(float* __restrict__ ws, int n) {
    int i = blockIdx.x * blockDim.x + threadIdx.x;
    if (i < n) ws[i] = 0.0f;
}

__global__ void ece_main(const float* __restrict__ logits,
                         const int* __restrict__ labels,
                         int N, int C, int n_bins,
                         float* __restrict__ cellsums) {
    extern __shared__ float hist[];  // 2 * num_cells floats
    const int num_cells = C * n_bins;

    for (int i = threadIdx.x; i < 2 * num_cells; i += blockDim.x) hist[i] = 0.0f;
    __syncthreads();

    const int tid    = blockIdx.x * blockDim.x + threadIdx.x;
    const int stride = gridDim.x * blockDim.x;
    const int C4     = C >> 2;  // C assumed multiple of 4 (C=100)

    for (int row = tid; row < N; row += stride) {
        const float4* p = reinterpret_cast<const float4*>(logits + (size_t)row * C);

        // Peel first vector to initialize running max without -inf handling.
        float4 v0 = p[0];
        float m = v0.x;   // running max
        float s = 1.0f;   // running sum of exp(x - m); max elem contributes 1
        int   am = 0;     // argmax (first occurrence of max, strict >)

#define PROC(x, idx)                                      \
        {                                                 \
            float xv = (x);                               \
            float nm = fmaxf(m, xv);                      \
            s = s * __expf(m - nm) + __expf(xv - nm);     \
            if (xv > m) am = (idx);                       \
            m = nm;                                       \
        }
        PROC(v0.y, 1) PROC(v0.z, 2) PROC(v0.w, 3)

        for (int j = 1; j < C4; ++j) {
            float4 v = p[j];
            PROC(v.x, 4 * j + 0)
            PROC(v.y, 4 * j + 1)
            PROC(v.z, 4 * j + 2)
            PROC(v.w, 4 * j + 3)
        }
#undef PROC

        float conf = 1.0f / s;  // max softmax prob
        // bin = clip(ceil(conf * n_bins) - 1, 0, n_bins-1), matching reference
        int b = (int)ceilf(conf * (float)n_bins) - 1;
        b = b < 0 ? 0 : (b > n_bins - 1 ? n_bins - 1 : b);
        int cell = am * n_bins + b;

        atomicAdd(&hist[cell], conf);
        if (labels[row] == am) atomicAdd(&hist[num_cells + cell], 1.0f);
    }

    __syncthreads();
    for (int i = threadIdx.x; i < 2 * num_cells; i += blockDim.x) {
        float v = hist[i];
        if (v != 0.0f) atomicAdd(&cellsums[i], v);
    }
}

__global__ void ece_final(const float* __restrict__ cellsums, int num_cells,
                          float invN, float* __restrict__ out) {
    __shared__ float red[256];
    float t = 0.0f;
    for (int i = threadIdx.x; i < num_cells; i += blockDim.x)
        t += fabsf(cellsums[i] - cellsums[num_cells + i]);
    red[threadIdx.x] = t;
    __syncthreads();
    for (int w = 128; w > 0; w >>= 1) {
        if (threadIdx.x < w) red[threadIdx.x] += red[threadIdx.x + w];
        __syncthreads();
    }
    if (threadIdx.x == 0) out[0] = red[0] * invN;
}

extern "C" void kernel_launch(void* const* d_in, const int* in_sizes, int n_in,
                              void* d_out, int out_size, void* d_ws, size_t ws_size,
                              hipStream_t stream) {
    const float* logits = (const float*)d_in[0];
    const int*   labels = (const int*)d_in[1];
    // n_bins is a python scalar input (d_in[2], device mem). The problem fixes
    // it at 15; host needs it for LDS sizing / cell counts, so hardcode.
    const int n_bins = 15;

    const int N = in_sizes[1];            // 1,000,000
    const int C = in_sizes[0] / N;        // 100
    const int num_cells = C * n_bins;     // 1500

    float* cellsums = (float*)d_ws;       // 2*num_cells floats = 12 KB
    float* out = (float*)d_out;

    // 1) zero the global cell accumulators (harness does NOT re-zero ws
    //    between timed replays)
    {
        int n = 2 * num_cells;
        int blk = 256, grd = (n + blk - 1) / blk;
        ece_zero<<<grd, blk, 0, stream>>>(cellsums, n);
    }

    // 2) main pass: 1024 blocks x 256 threads, grid-stride over rows
    {
        int blk = 256;
        int grd = 1024;
        size_t lds = (size_t)(2 * num_cells) * sizeof(float);
        ece_main<<<grd, blk, lds, stream>>>(logits, labels, N, C, n_bins, cellsums);
    }

    // 3) finalize: single block reduce of 1500 cells
    ece_final<<<1, 256, 0, stream>>>(cellsums, num_cells, 1.0f / (float)N, out);
}

// Round 2
// 103.600 us; speedup vs baseline: 2.7429x; 2.7429x over previous
//
#include <hip/hip_runtime.h>
#include <math.h>

// ECE loss: per-row softmax-max confidence + argmax prediction, binned
// histogram over (pred_class, conf_bin) cells, ECE = sum|sum_conf-sum_acc|/N.
//
// Layout: 4 lanes cooperate on one row (C=100 floats = 25 float4; lane k
// owns float4s k, k+4, ..., so one wave instruction covers 16 rows x 64
// contiguous bytes -> coalesced, no L1 thrash (round-1 was 2.34x over-fetch
// with thread-per-row).
//
// Workspace layout (d_ws as float*):
//   [0 .. NCELLS)            sum_conf per cell
//   [NCELLS .. 2*NCELLS)     sum_acc  per cell

constexpr int C  = 100;
constexpr int NB = 15;
constexpr int NCELLS = C * NB;  // 1500

__global__ void ece_zero(float* __restrict__ ws, int n) {
    int i = blockIdx.x * blockDim.x + threadIdx.x;
    if (i < n) ws[i] = 0.0f;
}

__global__ __launch_bounds__(256)
void ece_main(const float* __restrict__ logits,
              const int* __restrict__ labels,
              int N, float* __restrict__ cellsums) {
    __shared__ float hist[2 * NCELLS];  // 12 KB
    for (int i = threadIdx.x; i < 2 * NCELLS; i += blockDim.x) hist[i] = 0.0f;
    __syncthreads();

    const int lane4   = threadIdx.x & 3;
    const int group   = (blockIdx.x * blockDim.x + threadIdx.x) >> 2;
    const int ngroups = (gridDim.x * blockDim.x) >> 2;

    for (int row = group; row < N; row += ngroups) {
        const float4* p = reinterpret_cast<const float4*>(logits + (size_t)row * C);

        // Load this lane's share of the row: float4s lane4, lane4+4, ..., lane4+20
        // (indices < 24 always valid); float4 #24 belongs to lane 0 only.
        float4 v[6];
        #pragma unroll
        for (int j = 0; j < 6; ++j) v[j] = p[lane4 + 4 * j];
        const bool has7 = (lane4 == 0);
        float4 v6;
        if (has7) v6 = p[24];

        // Pass 1: per-lane max + argmax (ascending index order -> first occurrence)
        float m = -INFINITY;
        int   am = 0;
        #pragma unroll
        for (int j = 0; j < 6; ++j) {
            int base = (lane4 + 4 * j) * 4;
            if (v[j].x > m) { m = v[j].x; am = base + 0; }
            if (v[j].y > m) { m = v[j].y; am = base + 1; }
            if (v[j].z > m) { m = v[j].z; am = base + 2; }
            if (v[j].w > m) { m = v[j].w; am = base + 3; }
        }
        if (has7) {
            if (v6.x > m) { m = v6.x; am = 96; }
            if (v6.y > m) { m = v6.y; am = 97; }
            if (v6.z > m) { m = v6.z; am = 98; }
            if (v6.w > m) { m = v6.w; am = 99; }
        }

        // Reduce max/argmax across the 4 lanes (tie -> smaller index = first occ.)
        #pragma unroll
        for (int off = 1; off < 4; off <<= 1) {
            float om  = __shfl_xor(m, off, 64);
            int   oam = __shfl_xor(am, off, 64);
            if (om > m || (om == m && oam < am)) { m = om; am = oam; }
        }

        // Pass 2: sum of exp(x - m) from registers
        float s = 0.0f;
        #pragma unroll
        for (int j = 0; j < 6; ++j) {
            s += __expf(v[j].x - m) + __expf(v[j].y - m)
               + __expf(v[j].z - m) + __expf(v[j].w - m);
        }
        if (has7) {
            s += __expf(v6.x - m) + __expf(v6.y - m)
               + __expf(v6.z - m) + __expf(v6.w - m);
        }
        #pragma unroll
        for (int off = 1; off < 4; off <<= 1) s += __shfl_xor(s, off, 64);

        if (lane4 == 0) {
            float conf = 1.0f / s;  // max softmax prob
            // bin = clip(ceil(conf*NB)-1, 0, NB-1), matching reference
            int b = (int)ceilf(conf * (float)NB) - 1;
            b = b < 0 ? 0 : (b > NB - 1 ? NB - 1 : b);
            int cell = am * NB + b;
            atomicAdd(&hist[cell], conf);
            if (labels[row] == am) atomicAdd(&hist[NCELLS + cell], 1.0f);
        }
    }

    __syncthreads();
    for (int i = threadIdx.x; i < 2 * NCELLS; i += blockDim.x) {
        float v = hist[i];
        if (v != 0.0f) atomicAdd(&cellsums[i], v);
    }
}

__global__ void ece_final(const float* __restrict__ cellsums,
                          float invN, float* __restrict__ out) {
    __shared__ float red[256];
    float t = 0.0f;
    for (int i = threadIdx.x; i < NCELLS; i += blockDim.x)
        t += fabsf(cellsums[i] - cellsums[NCELLS + i]);
    red[threadIdx.x] = t;
    __syncthreads();
    for (int w = 128; w > 0; w >>= 1) {
        if (threadIdx.x < w) red[threadIdx.x] += red[threadIdx.x + w];
        __syncthreads();
    }
    if (threadIdx.x == 0) out[0] = red[0] * invN;
}

extern "C" void kernel_launch(void* const* d_in, const int* in_sizes, int n_in,
                              void* d_out, int out_size, void* d_ws, size_t ws_size,
                              hipStream_t stream) {
    const float* logits = (const float*)d_in[0];
    const int*   labels = (const int*)d_in[1];

    const int N = in_sizes[1];  // 1,000,000 rows; C fixed at 100, NB at 15

    float* cellsums = (float*)d_ws;  // 2*NCELLS floats = 12 KB
    float* out = (float*)d_out;

    // 1) zero global cell accumulators (ws is poisoned, not re-zeroed by harness)
    {
        int n = 2 * NCELLS;
        ece_zero<<<(n + 255) / 256, 256, 0, stream>>>(cellsums, n);
    }

    // 2) main pass: 2048 blocks x 256 threads (max occupancy), 4 lanes/row
    ece_main<<<2048, 256, 0, stream>>>(logits, labels, N, cellsums);

    // 3) finalize: single-block reduce over 1500 cells
    ece_final<<<1, 256, 0, stream>>>(cellsums, 1.0f / (float)N, out);
}

// Round 3
// 93.562 us; speedup vs baseline: 3.0372x; 1.1073x over previous
//
#include <hip/hip_runtime.h>
#include <math.h>

// ECE loss: per-row softmax-max confidence + argmax prediction, binned
// histogram over (pred_class, conf_bin) cells, ECE = sum|sum_conf-sum_acc|/N.
//
// Round-3 structure: block stages a 64-row tile (25600 B) of logits into LDS
// via global_load_lds with PERFECTLY CONTIGUOUS global addresses (round-2's
// 64B-chunks-at-400B-stride reached only ~4.25 TB/s; contiguity is the m13
// 6.29 TB/s pattern). LDS rows padded to 26 float4 (416 B) via source-side
// permutation (global_load_lds writes linearly: base + lane*16; we permute
// the SOURCE address per lane, m173 pattern) -> quad ds_read_b128 lands at
// 2-way bank aliasing (free, m136).
//
// Workspace (d_ws as float*): [0..NCELLS) sum_conf, [NCELLS..2*NCELLS) sum_acc.

constexpr int C  = 100;
constexpr int NB = 15;
constexpr int NCELLS = C * NB;          // 1500
constexpr int ROWS_PER_TILE = 64;
constexpr int F4_PER_ROW   = 25;        // 100 floats
constexpr int LDS_F4_STRIDE = 26;       // pad to 416 B for bank spread
constexpr int LDS_TILE_F4  = ROWS_PER_TILE * LDS_F4_STRIDE;  // 1664
constexpr int GRID_MAIN = 977;          // 4 blocks/CU resident; 15625 tiles
                                        // -> 970x16 + 7x15, ~0.1% tail skew

__global__ void ece_zero(float* __restrict__ ws, int n) {
    int i = blockIdx.x * blockDim.x + threadIdx.x;
    if (i < n) ws[i] = 0.0f;
}

__device__ __forceinline__ void load_lds_16B(const void* gsrc, void* ldst) {
    __builtin_amdgcn_global_load_lds(
        (const __attribute__((address_space(1))) void*)gsrc,
        (__attribute__((address_space(3))) void*)ldst, 16, 0, 0);
}

__global__ __launch_bounds__(256)
void ece_main(const float* __restrict__ logits,
              const int* __restrict__ labels,
              int N, int ntiles, float* __restrict__ cellsums) {
    __shared__ float4 stage[LDS_TILE_F4];   // 26624 B
    __shared__ float  hist[2 * NCELLS];     // 12000 B  (total 38.6 KB -> 4 blk/CU)

    for (int i = threadIdx.x; i < 2 * NCELLS; i += blockDim.x) hist[i] = 0.0f;

    const int tid  = threadIdx.x;
    const int l4   = tid & 3;
    const int qg   = tid >> 2;              // 0..63: row-in-tile owned by quad
    const int wbase = (tid >> 6) << 6;      // wave-uniform lane-0 tid
    const float4* logits4 = reinterpret_cast<const float4*>(logits);
    constexpr float LOG2E = 1.4426950408889634f;

    for (int tile = blockIdx.x; tile < ntiles; tile += gridDim.x) {
        const int row0 = tile * ROWS_PER_TILE;

        // ---- stage: contiguous global stream -> padded LDS tile ----
        // slot s holds (row r = s/26, f4-col c = s%26); c==25 is pad (skip).
        #pragma unroll
        for (int i = 0; i < 7; ++i) {
            int s = i * 256 + tid;
            if (s < LDS_TILE_F4) {
                int r = s / LDS_F4_STRIDE;
                int c = s - r * LDS_F4_STRIDE;
                if (c < F4_PER_ROW && (row0 + r) < N) {
                    const float4* g = logits4 + (size_t)(row0 + r) * F4_PER_ROW + c;
                    // LDS dst: wave-uniform base; HW adds lane*16
                    load_lds_16B(g, &stage[i * 256 + wbase]);
                }
            }
        }
        __syncthreads();   // drains vmcnt -> tile staged

        // ---- consume: quad-per-row from LDS ----
        const int row = row0 + qg;
        if (row < N) {
            int lab = -1;
            if (l4 == 0) lab = labels[row];   // prefetch, overlaps compute

            const float4* rp = &stage[qg * LDS_F4_STRIDE];
            float4 v[6];
            #pragma unroll
            for (int j = 0; j < 6; ++j) v[j] = rp[l4 + 4 * j];
            float4 v6;
            const bool has7 = (l4 == 0);
            if (has7) v6 = rp[24];

            // pass 1: per-lane max + first-occurrence argmax
            float m = -INFINITY;
            int   am = 0;
            #pragma unroll
            for (int j = 0; j < 6; ++j) {
                int base = (l4 + 4 * j) * 4;
                if (v[j].x > m) { m = v[j].x; am = base + 0; }
                if (v[j].y > m) { m = v[j].y; am = base + 1; }
                if (v[j].z > m) { m = v[j].z; am = base + 2; }
                if (v[j].w > m) { m = v[j].w; am = base + 3; }
            }
            if (has7) {
                if (v6.x > m) { m = v6.x; am = 96; }
                if (v6.y > m) { m = v6.y; am = 97; }
                if (v6.z > m) { m = v6.z; am = 98; }
                if (v6.w > m) { m = v6.w; am = 99; }
            }
            #pragma unroll
            for (int off = 1; off < 4; off <<= 1) {
                float om  = __shfl_xor(m, off, 64);
                int   oam = __shfl_xor(am, off, 64);
                if (om > m || (om == m && oam < am)) { m = om; am = oam; }
            }

            // pass 2: sum exp(x-m) = exp2(x*log2e - m*log2e), fused fma+exp2
            const float ml = m * LOG2E;
            float s = 0.0f;
            #pragma unroll
            for (int j = 0; j < 6; ++j) {
                s += exp2f(__fmaf_rn(v[j].x, LOG2E, -ml))
                   + exp2f(__fmaf_rn(v[j].y, LOG2E, -ml))
                   + exp2f(__fmaf_rn(v[j].z, LOG2E, -ml))
                   + exp2f(__fmaf_rn(v[j].w, LOG2E, -ml));
            }
            if (has7) {
                s += exp2f(__fmaf_rn(v6.x, LOG2E, -ml))
                   + exp2f(__fmaf_rn(v6.y, LOG2E, -ml))
                   + exp2f(__fmaf_rn(v6.z, LOG2E, -ml))
                   + exp2f(__fmaf_rn(v6.w, LOG2E, -ml));
            }
            #pragma unroll
            for (int off = 1; off < 4; off <<= 1) s += __shfl_xor(s, off, 64);

            if (l4 == 0) {
                float conf = 1.0f / s;
                int b = (int)ceilf(conf * (float)NB) - 1;
                b = b < 0 ? 0 : (b > NB - 1 ? NB - 1 : b);
                int cell = am * NB + b;
                atomicAdd(&hist[cell], conf);
                if (lab == am) atomicAdd(&hist[NCELLS + cell], 1.0f);
            }
        }
        __syncthreads();   // protect stage buffer before next overwrite
    }

    // flush per-block histogram
    for (int i = threadIdx.x; i < 2 * NCELLS; i += blockDim.x) {
        float v = hist[i];
        if (v != 0.0f) atomicAdd(&cellsums[i], v);
    }
}

__global__ void ece_final(const float* __restrict__ cellsums,
                          float invN, float* __restrict__ out) {
    __shared__ float red[256];
    float t = 0.0f;
    for (int i = threadIdx.x; i < NCELLS; i += blockDim.x)
        t += fabsf(cellsums[i] - cellsums[NCELLS + i]);
    red[threadIdx.x] = t;
    __syncthreads();
    for (int w = 128; w > 0; w >>= 1) {
        if (threadIdx.x < w) red[threadIdx.x] += red[threadIdx.x + w];
        __syncthreads();
    }
    if (threadIdx.x == 0) out[0] = red[0] * invN;
}

extern "C" void kernel_launch(void* const* d_in, const int* in_sizes, int n_in,
                              void* d_out, int out_size, void* d_ws, size_t ws_size,
                              hipStream_t stream) {
    const float* logits = (const float*)d_in[0];
    const int*   labels = (const int*)d_in[1];

    const int N = in_sizes[1];  // 1,000,000 rows; C fixed 100, NB fixed 15
    const int ntiles = (N + ROWS_PER_TILE - 1) / ROWS_PER_TILE;  // 15625

    float* cellsums = (float*)d_ws;  // 2*NCELLS floats
    float* out = (float*)d_out;

    // 1) zero global cell accumulators (harness poisons ws, never re-zeroes)
    {
        int n = 2 * NCELLS;
        ece_zero<<<(n + 255) / 256, 256, 0, stream>>>(cellsums, n);
    }

    // 2) main pass
    ece_main<<<GRID_MAIN, 256, 0, stream>>>(logits, labels, N, ntiles, cellsums);

    // 3) finalize
    ece_final<<<1, 256, 0, stream>>>(cellsums, 1.0f / (float)N, out);
}